// Round 7
// baseline (387.080 us; speedup 1.0000x reference)
//
#include <hip/hip_runtime.h>
#include <hip/hip_bf16.h>
#include <math.h>

#define NEG_INF (-1e9f)
#define B_   16
#define C_   192
#define TX   384
#define TY   1536
#define NWP  49            // padded decision-word stride
#define ROW_BYTES 1536     // TX * 4

#define BM 64
#define BN 64
#define BK 16

typedef float f32x2 __attribute__((ext_vector_type(2)));
typedef float f32x4 __attribute__((ext_vector_type(4)));

// ---------------------------------------------------------------------------
// K0: per-batch lengths tx, ty -> lens[2b], lens[2b+1]
// ---------------------------------------------------------------------------
__global__ __launch_bounds__(64) void k_len(const float* __restrict__ xm,
                                            const float* __restrict__ ym,
                                            int* __restrict__ lens) {
    const int b = blockIdx.x, l = threadIdx.x;
    int tx = 0, ty = 0;
#pragma unroll
    for (int i = 0; i < TX / 64; ++i)
        tx += __popcll(__ballot(xm[b * TX + i * 64 + l] > 0.5f));
#pragma unroll
    for (int i = 0; i < TY / 64; ++i)
        ty += __popcll(__ballot(ym[b * TY + i * 64 + l] > 0.5f));
    if (l == 0) { lens[2 * b] = tx; lens[2 * b + 1] = ty; }
}

// ---------------------------------------------------------------------------
// K1: per-(b,t) row constants r = logp1 + logp4
// ---------------------------------------------------------------------------
__global__ __launch_bounds__(128) void k_rowconst(const float* __restrict__ m_p,
                                                  const float* __restrict__ logs_p,
                                                  float* __restrict__ r) {
    const int b = blockIdx.y;
    const int t = blockIdx.x * 128 + threadIdx.x;
    const float* mp = m_p + b * C_ * TX + t;
    const float* lp = logs_p + b * C_ * TX + t;
    const float c0 = -0.9189385332046727f;  // -0.5*log(2*pi)
    float s = 0.0f;
    for (int c = 0; c < C_; ++c) {
        float ls = lp[c * TX];
        float m  = mp[c * TX];
        float os = expf(-2.0f * ls);
        s += (c0 - ls) - 0.5f * m * m * os;
    }
    r[b * TX + t] = s;
}

// ---------------------------------------------------------------------------
// K2: logp^T[b,s,t] ([B,Ty,Tx]). fp32 tiled GEMM, 64x64 tile, BK=16.
// Skips tiles with s >= ceil(ty/32)*32 (never read by the DP).
// Per-element fp32 accumulation order identical to previous rounds.
// ---------------------------------------------------------------------------
__global__ __launch_bounds__(256) void k_logp(const float* __restrict__ z_p,
                                              const float* __restrict__ m_p,
                                              const float* __restrict__ logs_p,
                                              const float* __restrict__ r,
                                              const int* __restrict__ lens,
                                              float* __restrict__ outT) {
    const int b   = blockIdx.z;
    const int sm0 = blockIdx.y * BM;   // s (Ty)
    const int ty_len = lens[2 * b + 1];
    if (sm0 >= ((ty_len + 31) & ~31)) return;   // rows never consumed

    __shared__ float Zs1[BK][BM];   // -0.5 z^2   (M-side = s/Ty)
    __shared__ float Zs2[BK][BM];   // z
    __shared__ float Ms1[BK][BN];   // os         (N-side = t/Tx)
    __shared__ float Ms2[BK][BN];   // m*os

    const int tn0 = blockIdx.x * BN;   // t (Tx)
    const int tid = threadIdx.x;
    const int lrow = tid >> 4;
    const int lcol = (tid & 15) << 2;
    const int tx_ = tid & 15;          // t quadrant
    const int ty_ = tid >> 4;          // s quadrant

    const float* mb = m_p + b * C_ * TX;
    const float* lb = logs_p + b * C_ * TX;
    const float* zb = z_p + b * C_ * TY;

    float acc[4][4] = {};

    for (int kk = 0; kk < C_; kk += BK) {
        float4 m4 = *(const float4*)(mb + (kk + lrow) * TX + tn0 + lcol);
        float4 l4 = *(const float4*)(lb + (kk + lrow) * TX + tn0 + lcol);
        float4 z4 = *(const float4*)(zb + (kk + lrow) * TY + sm0 + lcol);

        const float mm[4] = {m4.x, m4.y, m4.z, m4.w};
        const float ll[4] = {l4.x, l4.y, l4.z, l4.w};
        const float zz[4] = {z4.x, z4.y, z4.z, z4.w};
        float osv[4], a2v[4], u1v[4], u2v[4];
#pragma unroll
        for (int i = 0; i < 4; ++i) {
            float os = expf(-2.0f * ll[i]);
            osv[i] = os;
            a2v[i] = mm[i] * os;
            u1v[i] = -0.5f * zz[i] * zz[i];
            u2v[i] = zz[i];
        }

        __syncthreads();
#pragma unroll
        for (int i = 0; i < 4; ++i) {
            Ms1[lrow][lcol + i] = osv[i];
            Ms2[lrow][lcol + i] = a2v[i];
            Zs1[lrow][lcol + i] = u1v[i];
            Zs2[lrow][lcol + i] = u2v[i];
        }
        __syncthreads();

#pragma unroll
        for (int k = 0; k < BK; ++k) {
            float4 z1 = *(const float4*)&Zs1[k][ty_ * 4];
            float4 z2 = *(const float4*)&Zs2[k][ty_ * 4];
            float4 m1 = *(const float4*)&Ms1[k][tx_ * 4];
            float4 m2 = *(const float4*)&Ms2[k][tx_ * 4];
            const float u1a[4] = {z1.x, z1.y, z1.z, z1.w};
            const float u2a[4] = {z2.x, z2.y, z2.z, z2.w};
            const float a1a[4] = {m1.x, m1.y, m1.z, m1.w};
            const float a2a[4] = {m2.x, m2.y, m2.z, m2.w};
#pragma unroll
            for (int i = 0; i < 4; ++i)
#pragma unroll
                for (int j = 0; j < 4; ++j)
                    acc[i][j] = fmaf(a1a[j], u1a[i], fmaf(a2a[j], u2a[i], acc[i][j]));
        }
    }

    float4 r4 = *(const float4*)(r + b * TX + tn0 + tx_ * 4);
    const float rr[4] = {r4.x, r4.y, r4.z, r4.w};
#pragma unroll
    for (int i = 0; i < 4; ++i) {
        const int srow = sm0 + ty_ * 4 + i;
        float4 o;
        o.x = acc[i][0] + rr[0];
        o.y = acc[i][1] + rr[1];
        o.z = acc[i][2] + rr[2];
        o.w = acc[i][3] + rr[3];
        *(float4*)(outT + ((size_t)(b * TY + srow)) * TX + tn0 + tx_ * 4) = o;
    }
}

// ---------------------------------------------------------------------------
// K3: MAS DP. One wave per batch, 6 cells/lane, zero barriers, no masking.
// Loads: 2 asm VMEM ops/row (dwordx4+dwordx2), 16 rows in flight, counted
// vmcnt(30). Cross-lane neighbor value software-pipelined one step ahead via
// asm ds_bpermute + asm lgkmcnt, so DS latency hides under the step body.
// ---------------------------------------------------------------------------
__global__ __launch_bounds__(64) void k_dp(const float* __restrict__ logpT,
                                           const int* __restrict__ lens,
                                           int* __restrict__ idx_out) {
    extern __shared__ unsigned decw[];   // [TX][NWP]

    const int b = blockIdx.x;
    const int l = threadIdx.x;

    const int tx = lens[2 * b];
    const int ty = lens[2 * b + 1];
    const int yend = (ty + 31) & ~31;   // multiple of 32
    const int NBLK = yend >> 5;

    const char* pl = (const char*)(logpT + (size_t)b * TY * TX) + 24 * l;
    const int bperm_addr = (l - 1) * 4;   // lane-1 byte index (lane 0: wraps, unused)

    f32x4 Ra[16];
    f32x2 Rb[16];

#define ISSUE_ROW(u, row)                                                        \
    do {                                                                         \
        const char* _p = pl + (size_t)(row) * ROW_BYTES;                         \
        asm volatile("global_load_dwordx4 %0, %1, off"           : "=v"(Ra[u]) : "v"(_p)); \
        asm volatile("global_load_dwordx2 %0, %1, off offset:16" : "=v"(Rb[u]) : "v"(_p)); \
    } while (0)

    // prologue: rows 0..15 in flight (32 VMEM ops)
#pragma unroll
    for (int u = 0; u < 16; ++u) ISSUE_ROW(u, u);

    float v[6];
    unsigned w[6];
#pragma unroll
    for (int k = 0; k < 6; ++k) { v[k] = NEG_INF; w[k] = 0u; }

    float lane0vm = 0.0f;               // boundary for lane 0 at y=0; NEG_INF after
    const bool is_l0 = (l == 0);
    float vp5 = NEG_INF;                // neighbor v[5] for the CURRENT step

    int nextrow = 16;
    for (int blk = 0; blk < NBLK; ++blk) {
#pragma unroll
        for (int j = 0; j < 32; ++j) {
            const int u = j & 15;
            // gate on the 2 oldest VMEM ops (this slot's row)
            asm volatile("s_waitcnt vmcnt(30)" : "+v"(Ra[u]), "+v"(Rb[u]));
            float c0 = Ra[u].x, c1 = Ra[u].y, c2 = Ra[u].z;
            float c3 = Ra[u].w, c4 = Rb[u].x, c5 = Rb[u].y;

            // ---- k=5 first, then launch next step's neighbor exchange ----
            unsigned d5 = (v[5] < v[4]);
            float n5 = fmaxf(v[5], v[4]) + c5;
            float vp5n;
            asm volatile("ds_bpermute_b32 %0, %1, %2"
                         : "=v"(vp5n) : "v"(bperm_addr), "v"(n5));

            w[5] = w[5] + w[5] + d5;
            w[4] = w[4] + w[4] + (v[4] < v[3]);  float n4 = fmaxf(v[4], v[3]) + c4;
            w[3] = w[3] + w[3] + (v[3] < v[2]);  float n3 = fmaxf(v[3], v[2]) + c3;
            w[2] = w[2] + w[2] + (v[2] < v[1]);  float n2 = fmaxf(v[2], v[1]) + c2;
            w[1] = w[1] + w[1] + (v[1] < v[0]);  float n1 = fmaxf(v[1], v[0]) + c1;

            // previous step's bpermute has long landed; wait pins the dep
            asm volatile("s_waitcnt lgkmcnt(0)" : "+v"(vp5));
            float vm0 = is_l0 ? lane0vm : vp5;
            w[0] = w[0] + w[0] + (v[0] < vm0);   float n0 = fmaxf(v[0], vm0) + c0;

            v[5] = n5; v[4] = n4; v[3] = n3; v[2] = n2; v[1] = n1; v[0] = n0;
            vp5 = vp5n;

            if (j == 0 && blk == 0) lane0vm = NEG_INF;   // after y=0 only

            // issue row (y+16) into this slot (WAR dep orders after reads above)
            {
                int nr = nextrow < TY ? nextrow : (TY - 1);
                ISSUE_ROW(u, nr);
                ++nextrow;
            }
        }
        const int x0 = 6 * l;
#pragma unroll
        for (int k = 0; k < 6; ++k) { decw[(x0 + k) * NWP + blk] = w[k]; w[k] = 0u; }
    }

    __syncthreads();

    // ---- fill inactive frames with -1 (parallel) ----
    for (int y = ty + l; y < TY; y += 64) idx_out[b * TY + y] = -1;

    // ---- backtrack: serial bit-chase, 3-deep speculative word prefetch ----
    if (l == 0) {
        int idx = tx - 1;
        int* io = idx_out + b * TY;
        int blk = (ty - 1) >> 5;
        auto W = [&](int i, int bb) -> unsigned {
            return (i >= 0) ? decw[i * NWP + bb] : 0u;
        };
        unsigned w0 = W(idx, blk), w1 = W(idx - 1, blk),
                 w2 = W(idx - 2, blk), w3 = W(idx - 3, blk);
        for (int y = ty - 1; y >= 0; --y) {
            const int nb = y >> 5;
            if (nb != blk) {
                blk = nb;
                w0 = W(idx, blk); w1 = W(idx - 1, blk);
                w2 = W(idx - 2, blk); w3 = W(idx - 3, blk);
            }
            io[y] = idx;
            if ((w0 >> (31 - (y & 31))) & 1u) {
                --idx;
                w0 = w1; w1 = w2; w2 = w3; w3 = W(idx - 3, blk);
            }
        }
    }
#undef ISSUE_ROW
}

// ---------------------------------------------------------------------------
// K4: write the one-hot path. Fully overwrites d_out (which held logp^T).
// ---------------------------------------------------------------------------
__global__ __launch_bounds__(384) void k_path(const int* __restrict__ idx_arr,
                                              float* __restrict__ out) {
    const int b = blockIdx.y;
    const int x = blockIdx.x;
    const int t = threadIdx.x;
    const int y0 = t * 4;
    int4 iv = *(const int4*)(idx_arr + b * TY + y0);
    float4 o;
    o.x = (iv.x == x) ? 1.0f : 0.0f;
    o.y = (iv.y == x) ? 1.0f : 0.0f;
    o.z = (iv.z == x) ? 1.0f : 0.0f;
    o.w = (iv.w == x) ? 1.0f : 0.0f;
    *(float4*)(out + ((size_t)(b * TX + x)) * TY + y0) = o;
}

// ---------------------------------------------------------------------------
extern "C" void kernel_launch(void* const* d_in, const int* in_sizes, int n_in,
                              void* d_out, int out_size, void* d_ws, size_t ws_size,
                              hipStream_t stream) {
    const float* z_p    = (const float*)d_in[0];
    const float* m_p    = (const float*)d_in[1];
    const float* logs_p = (const float*)d_in[2];
    const float* x_mask = (const float*)d_in[3];
    const float* y_mask = (const float*)d_in[4];
    float* out = (float*)d_out;

    float* r       = (float*)d_ws;                                    // B*TX floats
    int*   idx_arr = (int*)((char*)d_ws + B_ * TX * 4);               // B*TY ints
    int*   lens    = (int*)((char*)d_ws + B_ * TX * 4 + B_ * TY * 4); // 2*B ints

    // K3 dynamic LDS: 384 * 49 * 4 = 75264 B (> 64KB default cap)
    static const size_t dp_smem = (size_t)TX * NWP * 4;
    (void)hipFuncSetAttribute((const void*)k_dp,
                              hipFuncAttributeMaxDynamicSharedMemorySize,
                              (int)dp_smem);

    k_len<<<B_, 64, 0, stream>>>(x_mask, y_mask, lens);
    k_rowconst<<<dim3(TX / 128, B_), 128, 0, stream>>>(m_p, logs_p, r);
    k_logp<<<dim3(TX / BN, TY / BM, B_), 256, 0, stream>>>(z_p, m_p, logs_p, r, lens, out);
    k_dp<<<B_, 64, dp_smem, stream>>>(out, lens, idx_arr);
    k_path<<<dim3(TX, B_), TX, 0, stream>>>(idx_arr, out);
}

// Round 9
// 366.605 us; speedup vs baseline: 1.0558x; 1.0558x over previous
//
#include <hip/hip_runtime.h>
#include <hip/hip_bf16.h>
#include <math.h>

#define NEG_INF (-1e9f)
#define B_   16
#define C_   192
#define TX   384
#define TY   1536
#define NWP  49            // padded decision-word stride
#define ROW_BYTES 1536     // TX * 4

#define BM 64
#define BN 64
#define BK 16

typedef float f32x2 __attribute__((ext_vector_type(2)));
typedef float f32x4 __attribute__((ext_vector_type(4)));

// ---------------------------------------------------------------------------
// K0: per-batch lengths tx, ty -> lens[2b], lens[2b+1]
// ---------------------------------------------------------------------------
__global__ __launch_bounds__(64) void k_len(const float* __restrict__ xm,
                                            const float* __restrict__ ym,
                                            int* __restrict__ lens) {
    const int b = blockIdx.x, l = threadIdx.x;
    int tx = 0, ty = 0;
#pragma unroll
    for (int i = 0; i < TX / 64; ++i)
        tx += __popcll(__ballot(xm[b * TX + i * 64 + l] > 0.5f));
#pragma unroll
    for (int i = 0; i < TY / 64; ++i)
        ty += __popcll(__ballot(ym[b * TY + i * 64 + l] > 0.5f));
    if (l == 0) { lens[2 * b] = tx; lens[2 * b + 1] = ty; }
}

// ---------------------------------------------------------------------------
// K1: per-(b,t) row constants r = logp1 + logp4
// ---------------------------------------------------------------------------
__global__ __launch_bounds__(128) void k_rowconst(const float* __restrict__ m_p,
                                                  const float* __restrict__ logs_p,
                                                  float* __restrict__ r) {
    const int b = blockIdx.y;
    const int t = blockIdx.x * 128 + threadIdx.x;
    const float* mp = m_p + b * C_ * TX + t;
    const float* lp = logs_p + b * C_ * TX + t;
    const float c0 = -0.9189385332046727f;  // -0.5*log(2*pi)
    float s = 0.0f;
    for (int c = 0; c < C_; ++c) {
        float ls = lp[c * TX];
        float m  = mp[c * TX];
        float os = expf(-2.0f * ls);
        s += (c0 - ls) - 0.5f * m * m * os;
    }
    r[b * TX + t] = s;
}

// ---------------------------------------------------------------------------
// K2: logp^T[b,s,t] ([B,Ty,Tx]). fp32 tiled GEMM, 64x64 tile, BK=16.
// Skips tiles with s >= ceil(ty/32)*32 (never read by the DP).
// Per-element fp32 accumulation order identical to previous rounds.
// ---------------------------------------------------------------------------
__global__ __launch_bounds__(256) void k_logp(const float* __restrict__ z_p,
                                              const float* __restrict__ m_p,
                                              const float* __restrict__ logs_p,
                                              const float* __restrict__ r,
                                              const int* __restrict__ lens,
                                              float* __restrict__ outT) {
    const int b   = blockIdx.z;
    const int sm0 = blockIdx.y * BM;   // s (Ty)
    const int ty_len = lens[2 * b + 1];
    if (sm0 >= ((ty_len + 31) & ~31)) return;   // rows never consumed

    __shared__ float Zs1[BK][BM];   // -0.5 z^2   (M-side = s/Ty)
    __shared__ float Zs2[BK][BM];   // z
    __shared__ float Ms1[BK][BN];   // os         (N-side = t/Tx)
    __shared__ float Ms2[BK][BN];   // m*os

    const int tn0 = blockIdx.x * BN;   // t (Tx)
    const int tid = threadIdx.x;
    const int lrow = tid >> 4;
    const int lcol = (tid & 15) << 2;
    const int tx_ = tid & 15;          // t quadrant
    const int ty_ = tid >> 4;          // s quadrant

    const float* mb = m_p + b * C_ * TX;
    const float* lb = logs_p + b * C_ * TX;
    const float* zb = z_p + b * C_ * TY;

    float acc[4][4] = {};

    for (int kk = 0; kk < C_; kk += BK) {
        float4 m4 = *(const float4*)(mb + (kk + lrow) * TX + tn0 + lcol);
        float4 l4 = *(const float4*)(lb + (kk + lrow) * TX + tn0 + lcol);
        float4 z4 = *(const float4*)(zb + (kk + lrow) * TY + sm0 + lcol);

        const float mm[4] = {m4.x, m4.y, m4.z, m4.w};
        const float ll[4] = {l4.x, l4.y, l4.z, l4.w};
        const float zz[4] = {z4.x, z4.y, z4.z, z4.w};
        float osv[4], a2v[4], u1v[4], u2v[4];
#pragma unroll
        for (int i = 0; i < 4; ++i) {
            float os = expf(-2.0f * ll[i]);
            osv[i] = os;
            a2v[i] = mm[i] * os;
            u1v[i] = -0.5f * zz[i] * zz[i];
            u2v[i] = zz[i];
        }

        __syncthreads();
#pragma unroll
        for (int i = 0; i < 4; ++i) {
            Ms1[lrow][lcol + i] = osv[i];
            Ms2[lrow][lcol + i] = a2v[i];
            Zs1[lrow][lcol + i] = u1v[i];
            Zs2[lrow][lcol + i] = u2v[i];
        }
        __syncthreads();

#pragma unroll
        for (int k = 0; k < BK; ++k) {
            float4 z1 = *(const float4*)&Zs1[k][ty_ * 4];
            float4 z2 = *(const float4*)&Zs2[k][ty_ * 4];
            float4 m1 = *(const float4*)&Ms1[k][tx_ * 4];
            float4 m2 = *(const float4*)&Ms2[k][tx_ * 4];
            const float u1a[4] = {z1.x, z1.y, z1.z, z1.w};
            const float u2a[4] = {z2.x, z2.y, z2.z, z2.w};
            const float a1a[4] = {m1.x, m1.y, m1.z, m1.w};
            const float a2a[4] = {m2.x, m2.y, m2.z, m2.w};
#pragma unroll
            for (int i = 0; i < 4; ++i)
#pragma unroll
                for (int j = 0; j < 4; ++j)
                    acc[i][j] = fmaf(a1a[j], u1a[i], fmaf(a2a[j], u2a[i], acc[i][j]));
        }
    }

    float4 r4 = *(const float4*)(r + b * TX + tn0 + tx_ * 4);
    const float rr[4] = {r4.x, r4.y, r4.z, r4.w};
#pragma unroll
    for (int i = 0; i < 4; ++i) {
        const int srow = sm0 + ty_ * 4 + i;
        float4 o;
        o.x = acc[i][0] + rr[0];
        o.y = acc[i][1] + rr[1];
        o.z = acc[i][2] + rr[2];
        o.w = acc[i][3] + rr[3];
        *(float4*)(outT + ((size_t)(b * TY + srow)) * TX + tn0 + tx_ * 4) = o;
    }
}

// ---------------------------------------------------------------------------
// K3: MAS DP. One wave per batch, 6 cells/lane, zero barriers, no masking.
// Loads: 2 asm VMEM ops/row (dwordx4+dwordx2), 16 rows in flight, counted
// vmcnt(30). Neighbor exchange entirely on the VALU: update_dpp row_shr:1 +
// asm v_writelane_b32 fixups for lanes 16/32/48 — no DS op, no lgkm wait
// anywhere in the main loop.
// ---------------------------------------------------------------------------
__global__ __launch_bounds__(64) void k_dp(const float* __restrict__ logpT,
                                           const int* __restrict__ lens,
                                           int* __restrict__ idx_out) {
    extern __shared__ unsigned decw[];   // [TX][NWP]

    const int b = blockIdx.x;
    const int l = threadIdx.x;

    const int tx = lens[2 * b];
    const int ty = lens[2 * b + 1];
    const int yend = (ty + 31) & ~31;   // multiple of 32
    const int NBLK = yend >> 5;

    const char* pl = (const char*)(logpT + (size_t)b * TY * TX) + 24 * l;

    f32x4 Ra[16];
    f32x2 Rb[16];

#define ISSUE_ROW(u, row)                                                        \
    do {                                                                         \
        const char* _p = pl + (size_t)(row) * ROW_BYTES;                         \
        asm volatile("global_load_dwordx4 %0, %1, off"           : "=v"(Ra[u]) : "v"(_p)); \
        asm volatile("global_load_dwordx2 %0, %1, off offset:16" : "=v"(Rb[u]) : "v"(_p)); \
    } while (0)

    // prologue: rows 0..15 in flight (32 VMEM ops)
#pragma unroll
    for (int u = 0; u < 16; ++u) ISSUE_ROW(u, u);

    float v[6];
    unsigned w[6];
#pragma unroll
    for (int k = 0; k < 6; ++k) { v[k] = NEG_INF; w[k] = 0u; }

    float lane0vm = 0.0f;               // boundary for lane 0 at y=0; NEG_INF after
    const bool is_l0 = (l == 0);

    int nextrow = 16;
    for (int blk = 0; blk < NBLK; ++blk) {
#pragma unroll
        for (int j = 0; j < 32; ++j) {
            const int u = j & 15;
            // gate on the 2 oldest VMEM ops (this slot's row)
            asm volatile("s_waitcnt vmcnt(30)" : "+v"(Ra[u]), "+v"(Rb[u]));
            float c0 = Ra[u].x, c1 = Ra[u].y, c2 = Ra[u].z;
            float c3 = Ra[u].w, c4 = Rb[u].x, c5 = Rb[u].y;

            // ---- neighbor exchange on the VALU (shift-up-1 across 64 lanes) ----
            const int v5i = __float_as_int(v[5]);
            const int s15 = __builtin_amdgcn_readlane(v5i, 15);
            const int s31 = __builtin_amdgcn_readlane(v5i, 31);
            const int s47 = __builtin_amdgcn_readlane(v5i, 47);
            int vpi = __builtin_amdgcn_update_dpp(0, v5i, 0x111, 0xF, 0xF, false);
            asm("v_writelane_b32 %0, %1, 16" : "+v"(vpi) : "s"(s15));
            asm("v_writelane_b32 %0, %1, 32" : "+v"(vpi) : "s"(s31));
            asm("v_writelane_b32 %0, %1, 48" : "+v"(vpi) : "s"(s47));
            const float vp5 = __int_as_float(vpi);
            const float vm0 = is_l0 ? lane0vm : vp5;

            // ---- DP step (no masking; bit-identical decisions) ----
            w[5] = w[5] + w[5] + (v[5] < v[4]);  float n5 = fmaxf(v[5], v[4]) + c5;
            w[4] = w[4] + w[4] + (v[4] < v[3]);  float n4 = fmaxf(v[4], v[3]) + c4;
            w[3] = w[3] + w[3] + (v[3] < v[2]);  float n3 = fmaxf(v[3], v[2]) + c3;
            w[2] = w[2] + w[2] + (v[2] < v[1]);  float n2 = fmaxf(v[2], v[1]) + c2;
            w[1] = w[1] + w[1] + (v[1] < v[0]);  float n1 = fmaxf(v[1], v[0]) + c1;
            w[0] = w[0] + w[0] + (v[0] < vm0);   float n0 = fmaxf(v[0], vm0) + c0;
            v[5] = n5; v[4] = n4; v[3] = n3; v[2] = n2; v[1] = n1; v[0] = n0;

            if (j == 0 && blk == 0) lane0vm = NEG_INF;   // after y=0 only

            // issue row (y+16) into this slot (WAR dep orders after reads above)
            {
                int nr = nextrow < TY ? nextrow : (TY - 1);
                ISSUE_ROW(u, nr);
                ++nextrow;
            }
        }
        const int x0 = 6 * l;
#pragma unroll
        for (int k = 0; k < 6; ++k) { decw[(x0 + k) * NWP + blk] = w[k]; w[k] = 0u; }
    }

    __syncthreads();   // also drains in-flight asm loads (vmcnt(0) before barrier)

    // ---- fill inactive frames with -1 (parallel) ----
    for (int y = ty + l; y < TY; y += 64) idx_out[b * TY + y] = -1;

    // ---- backtrack: serial bit-chase, 3-deep speculative word prefetch ----
    if (l == 0) {
        int idx = tx - 1;
        int* io = idx_out + b * TY;
        int blk = (ty - 1) >> 5;
        auto W = [&](int i, int bb) -> unsigned {
            return (i >= 0) ? decw[i * NWP + bb] : 0u;
        };
        unsigned w0 = W(idx, blk), w1 = W(idx - 1, blk),
                 w2 = W(idx - 2, blk), w3 = W(idx - 3, blk);
        for (int y = ty - 1; y >= 0; --y) {
            const int nb = y >> 5;
            if (nb != blk) {
                blk = nb;
                w0 = W(idx, blk); w1 = W(idx - 1, blk);
                w2 = W(idx - 2, blk); w3 = W(idx - 3, blk);
            }
            io[y] = idx;
            if ((w0 >> (31 - (y & 31))) & 1u) {
                --idx;
                w0 = w1; w1 = w2; w2 = w3; w3 = W(idx - 3, blk);
            }
        }
    }
#undef ISSUE_ROW
}

// ---------------------------------------------------------------------------
// K4: write the one-hot path. Fully overwrites d_out (which held logp^T).
// ---------------------------------------------------------------------------
__global__ __launch_bounds__(384) void k_path(const int* __restrict__ idx_arr,
                                              float* __restrict__ out) {
    const int b = blockIdx.y;
    const int x = blockIdx.x;
    const int t = threadIdx.x;
    const int y0 = t * 4;
    int4 iv = *(const int4*)(idx_arr + b * TY + y0);
    float4 o;
    o.x = (iv.x == x) ? 1.0f : 0.0f;
    o.y = (iv.y == x) ? 1.0f : 0.0f;
    o.z = (iv.z == x) ? 1.0f : 0.0f;
    o.w = (iv.w == x) ? 1.0f : 0.0f;
    *(float4*)(out + ((size_t)(b * TX + x)) * TY + y0) = o;
}

// ---------------------------------------------------------------------------
extern "C" void kernel_launch(void* const* d_in, const int* in_sizes, int n_in,
                              void* d_out, int out_size, void* d_ws, size_t ws_size,
                              hipStream_t stream) {
    const float* z_p    = (const float*)d_in[0];
    const float* m_p    = (const float*)d_in[1];
    const float* logs_p = (const float*)d_in[2];
    const float* x_mask = (const float*)d_in[3];
    const float* y_mask = (const float*)d_in[4];
    float* out = (float*)d_out;

    float* r       = (float*)d_ws;                                    // B*TX floats
    int*   idx_arr = (int*)((char*)d_ws + B_ * TX * 4);               // B*TY ints
    int*   lens    = (int*)((char*)d_ws + B_ * TX * 4 + B_ * TY * 4); // 2*B ints

    // K3 dynamic LDS: 384 * 49 * 4 = 75264 B (> 64KB default cap)
    static const size_t dp_smem = (size_t)TX * NWP * 4;
    (void)hipFuncSetAttribute((const void*)k_dp,
                              hipFuncAttributeMaxDynamicSharedMemorySize,
                              (int)dp_smem);

    k_len<<<B_, 64, 0, stream>>>(x_mask, y_mask, lens);
    k_rowconst<<<dim3(TX / 128, B_), 128, 0, stream>>>(m_p, logs_p, r);
    k_logp<<<dim3(TX / BN, TY / BM, B_), 256, 0, stream>>>(z_p, m_p, logs_p, r, lens, out);
    k_dp<<<B_, 64, dp_smem, stream>>>(out, lens, idx_arr);
    k_path<<<dim3(TX, B_), TX, 0, stream>>>(idx_arr, out);
}